// Round 4
// baseline (12585.191 us; speedup 1.0000x reference)
//
#include <hip/hip_runtime.h>
#include <math.h>

#define SS 512
#define BB 32
#define HH 256
#define G4 1024
#define TT 11
#define NEGV (-1000.0f)

// ---------------- workspace layout (bytes) ----------------
static const size_t OFF_XE    = 0;                          // 16,777,216  : xe [B*S][256]
static const size_t OFF_XS    = 16777216ull;                // 134,217,728 : xs [2][S][B][1024]
static const size_t OFF_H0    = OFF_XS + 134217728ull;      // 33,554,432  : h0 [B*S][512]
static const size_t OFF_H1    = OFF_H0 + 33554432ull;       // 33,554,432  : h1 [B*S][512]
static const size_t OFF_FEATS = OFF_H1 + 33554432ull;       // 720,896     : feats [B][S][11]
static const size_t OFF_HBUF  = OFF_FEATS + 720896ull;      // 262,144     : tagged h ping-pong [2 dir][2][32 b][256 col] u64
// total ~219 MB

// ---------------- embedding gather ----------------
__global__ void emb_kernel(const int* __restrict__ x, const float4* __restrict__ emb,
                           float4* __restrict__ xe) {
  int idx = blockIdx.x * 256 + threadIdx.x;    // over B*S*H/4 = 1,048,576
  int bs  = idx >> 6;
  int kq  = idx & 63;
  int row = x[bs];
  xe[idx] = emb[(size_t)row * 64 + kq];
}

// ---------------- input projection GEMM ----------------
// C[m][n] = sum_k A[m][k]*W[n][k] + bias[n]  -> xs[dir][s][b][n], m = b*S+s
// 128x128 tile, 256 threads, 8x8 micro-tile, BK=8
template<int K>
__global__ __launch_bounds__(256, 2)
void proj_kernel(const float* __restrict__ A,
                 const float* __restrict__ Wf, const float* __restrict__ Wb,
                 const float* __restrict__ bf, const float* __restrict__ bb,
                 float* __restrict__ xs) {
  __shared__ float As[8][132];
  __shared__ float Bs[8][132];
  int tid = threadIdx.x;
  int dir = blockIdx.z;
  const float* W    = dir ? Wb : Wf;
  const float* bias = dir ? bb : bf;
  float* out = xs + (size_t)dir * (SS * BB * G4);
  int bm = blockIdx.x * 128;
  int bn = blockIdx.y * 128;
  int ty = tid >> 4;
  int tx = tid & 15;
  int lr = tid >> 1;
  int lk = (tid & 1) * 4;
  const float* Ap = A + (size_t)(bm + lr) * K + lk;
  const float* Wp = W + (size_t)(bn + lr) * K + lk;
  float acc[8][8];
  #pragma unroll
  for (int i = 0; i < 8; i++)
    #pragma unroll
    for (int j = 0; j < 8; j++) acc[i][j] = 0.f;

  for (int kt = 0; kt < K; kt += 8) {
    float4 av = *(const float4*)(Ap + kt);
    float4 bv = *(const float4*)(Wp + kt);
    __syncthreads();
    As[lk + 0][lr] = av.x; As[lk + 1][lr] = av.y; As[lk + 2][lr] = av.z; As[lk + 3][lr] = av.w;
    Bs[lk + 0][lr] = bv.x; Bs[lk + 1][lr] = bv.y; Bs[lk + 2][lr] = bv.z; Bs[lk + 3][lr] = bv.w;
    __syncthreads();
    #pragma unroll
    for (int k = 0; k < 8; k++) {
      float4 a0 = *(const float4*)&As[k][ty * 8];
      float4 a1 = *(const float4*)&As[k][ty * 8 + 4];
      float4 b0 = *(const float4*)&Bs[k][tx * 8];
      float4 b1 = *(const float4*)&Bs[k][tx * 8 + 4];
      float a[8] = {a0.x, a0.y, a0.z, a0.w, a1.x, a1.y, a1.z, a1.w};
      float b[8] = {b0.x, b0.y, b0.z, b0.w, b1.x, b1.y, b1.z, b1.w};
      #pragma unroll
      for (int i = 0; i < 8; i++)
        #pragma unroll
        for (int j = 0; j < 8; j++)
          acc[i][j] += a[i] * b[j];
    }
  }
  int nb = bn + tx * 8;
  float4 bias0 = *(const float4*)(bias + nb);
  float4 bias1 = *(const float4*)(bias + nb + 4);
  #pragma unroll
  for (int i = 0; i < 8; i++) {
    int gm = bm + ty * 8 + i;
    int b_ = gm >> 9;
    int s_ = gm & 511;
    float* op = out + (size_t)(s_ * BB + b_) * G4 + nb;
    float4 v0, v1;
    v0.x = acc[i][0] + bias0.x; v0.y = acc[i][1] + bias0.y;
    v0.z = acc[i][2] + bias0.z; v0.w = acc[i][3] + bias0.w;
    v1.x = acc[i][4] + bias1.x; v1.y = acc[i][5] + bias1.y;
    v1.z = acc[i][6] + bias1.z; v1.w = acc[i][7] + bias1.w;
    *(float4*)op = v0;
    *(float4*)(op + 4) = v1;
  }
}

// ---------------- recurrent scan (one bidirectional LSTM layer) ----------------
// grid (64, 2): blockIdx.x = cell-group (4 cells), blockIdx.y = direction.
// SELF-PUBLISHING TAGGED DATA (no flags, no fences, no wbl2):
//   h element = one u64 word: (step_tag << 32) | f32_bits. Producers publish h
//   for step s+1 with a single relaxed agent-scope 8B atomic store (tag s+1);
//   consumers at step s poll their k-slice words until all tags == s. One MALL
//   store->load round trip producer-to-consumer; retries reload only
//   not-yet-arrived words (per-lane bad mask).
//   WAR safety (2 ping-pong buffers): a block's tag-(s+1) stores are program-
//   order AFTER its step-s reads of buf[s&1]; any block seeing all tags s+1
//   therefore knows buf[(s+1)&1]'s previous readers (step s... same-parity
//   buffer read at step s-1, whose reads precede those blocks' tag-s stores,
//   which precede their tag-(s+1) stores) are done. Verified chain per step.
__global__ __launch_bounds__(256, 1)
void scan_kernel(const float* __restrict__ xs,      // [2][S][B][1024]
                 const float* __restrict__ whhf, const float* __restrict__ whhb,
                 unsigned long long* __restrict__ hbuf8,  // [2 dir][2 buf][32 b][256 col]
                 float* __restrict__ hout)          // [B*S][512]
{
  int tid = threadIdx.x;
  int cb  = blockIdx.x;           // 0..63
  int dir = blockIdx.y;
  const float* whh = dir ? whhb : whhf;
  const float* xsd = xs + (size_t)dir * (SS * BB * G4);
  unsigned long long* hb = hbuf8 + (size_t)dir * (2 * BB * HH);

  __shared__ float h_sh[32 * 260];       // h[b][k] padded: row stride 260 floats
  __shared__ float part[4 * 16 * 33];    // partial[w][row_local][b]

  int w    = tid >> 6;           // wave index = k-slice owner
  int lane = tid & 63;
  int r8   = lane >> 3;          // row pair: rows r8*2, r8*2+1
  int b8   = lane & 7;           // batches b8 + 8*jb
  int col  = w * 64 + lane;      // this lane's staged column (within full 256)

  // preload weights into registers: wreg[i][j] = whh[grow(r8*2+i)][w*64 + j*4 ..+3]
  float4 wreg[2][16];
  #pragma unroll
  for (int i = 0; i < 2; i++) {
    int rl   = r8 * 2 + i;
    int grow = (rl >> 2) * 256 + cb * 4 + (rl & 3);
    const float* wp = whh + (size_t)grow * 256 + w * 64;
    #pragma unroll
    for (int j = 0; j < 16; j++) wreg[i][j] = *(const float4*)(wp + j * 4);
  }

  int uc = tid >> 5;    // cell 0..3 (valid for tid<128)
  int ub = tid & 31;    // batch
  float c_state = 0.f;

  for (int s = 0; s < SS; ++s) {
    int tpos = dir ? (SS - 1 - s) : s;

    // prefetch xs gate biases (normal loads, warm L2/L3) BEFORE the poll
    float xsg[4] = {0.f, 0.f, 0.f, 0.f};
    if (tid < 128) {
      const float* xp = xsd + ((size_t)(tpos * BB + ub) * G4) + cb * 4 + uc;
      #pragma unroll
      for (int g = 0; g < 4; g++) xsg[g] = xp[g * 256];
    }

    // ---- poll+stage this wave's k-slice: 32 batches x 1 col/lane ----
    {
      const unsigned long long* src = hb + (size_t)(s & 1) * (BB * HH) + col;
      unsigned long long raw[32];
      #pragma unroll
      for (int i = 0; i < 32; i++)
        raw[i] = __hip_atomic_load(src + i * HH, __ATOMIC_RELAXED, __HIP_MEMORY_SCOPE_AGENT);
      // write all to LDS unconditionally (bad slots corrected below, before use)
      #pragma unroll
      for (int i = 0; i < 32; i++) {
        unsigned lo = (unsigned)raw[i];
        float t; __builtin_memcpy(&t, &lo, 4);
        h_sh[i * 260 + col] = t;
      }
      unsigned bad = 0u;
      #pragma unroll
      for (int i = 0; i < 32; i++)
        if ((unsigned)(raw[i] >> 32) != (unsigned)s) bad |= (1u << i);
      while (__any(bad != 0u)) {
        #pragma unroll
        for (int i = 0; i < 32; i++) {
          if (bad & (1u << i)) {
            unsigned long long r =
                __hip_atomic_load(src + i * HH, __ATOMIC_RELAXED, __HIP_MEMORY_SCOPE_AGENT);
            if ((unsigned)(r >> 32) == (unsigned)s) {
              unsigned lo = (unsigned)r;
              float t; __builtin_memcpy(&t, &lo, 4);
              h_sh[i * 260 + col] = t;
              bad &= ~(1u << i);
            }
          }
        }
      }
    }
    // no cross-wave barrier needed: wave w wrote & reads only cols [w*64,w*64+64)

    // partial dot products over this wave's k-slice
    float acc[2][4] = {{0.f,0.f,0.f,0.f},{0.f,0.f,0.f,0.f}};
    #pragma unroll
    for (int j = 0; j < 16; j++) {
      int k4 = w * 16 + j;
      float4 h0 = *(const float4*)&h_sh[(b8 +  0) * 260 + k4 * 4];
      float4 h1 = *(const float4*)&h_sh[(b8 +  8) * 260 + k4 * 4];
      float4 h2 = *(const float4*)&h_sh[(b8 + 16) * 260 + k4 * 4];
      float4 h3 = *(const float4*)&h_sh[(b8 + 24) * 260 + k4 * 4];
      #pragma unroll
      for (int i = 0; i < 2; i++) {
        float4 wv = wreg[i][j];
        acc[i][0] += wv.x * h0.x + wv.y * h0.y + wv.z * h0.z + wv.w * h0.w;
        acc[i][1] += wv.x * h1.x + wv.y * h1.y + wv.z * h1.z + wv.w * h1.w;
        acc[i][2] += wv.x * h2.x + wv.y * h2.y + wv.z * h2.z + wv.w * h2.w;
        acc[i][3] += wv.x * h3.x + wv.y * h3.y + wv.z * h3.z + wv.w * h3.w;
      }
    }
    #pragma unroll
    for (int i = 0; i < 2; i++) {
      int rl = r8 * 2 + i;
      #pragma unroll
      for (int jb = 0; jb < 4; jb++)
        part[(w * 16 + rl) * 33 + (b8 + 8 * jb)] = acc[i][jb];
    }
    __syncthreads();

    // reduce + LSTM cell update (threads 0..127: 4 cells x 32 batches)
    if (tid < 128) {
      float gv[4];
      #pragma unroll
      for (int g = 0; g < 4; g++) {
        int rl = g * 4 + uc;
        float sum = xsg[g];
        #pragma unroll
        for (int ww = 0; ww < 4; ww++) sum += part[(ww * 16 + rl) * 33 + ub];
        gv[g] = sum;
      }
      float ig = 1.f / (1.f + expf(-gv[0]));
      float fg = 1.f / (1.f + expf(-gv[1]));
      float gg = tanhf(gv[2]);
      float og = 1.f / (1.f + expf(-gv[3]));
      c_state = fg * c_state + ig * gg;
      float hv = og * tanhf(c_state);
      int colp = cb * 4 + uc;
      // publish tagged h for step s+1 (single 8B atomic store; self-flagging)
      unsigned hv_bits; __builtin_memcpy(&hv_bits, &hv, 4);
      unsigned long long pack = ((unsigned long long)(unsigned)(s + 1) << 32) | hv_bits;
      __hip_atomic_store(&hb[(size_t)((s + 1) & 1) * (BB * HH) + ub * HH + colp], pack,
                         __ATOMIC_RELAXED, __HIP_MEMORY_SCOPE_AGENT);
      hout[((size_t)(ub * SS + tpos)) * 512 + dir * 256 + colp] = hv;   // normal store
    }

    // protect `part` (read by waves 0-1 above) from next-step overwrites by
    // waves whose poll doesn't include this block's own columns.
    __syncthreads();
  }
}

// ---------------- emission features ----------------
__global__ void feats_kernel(const float* __restrict__ h1, const float* __restrict__ wout,
                             const float* __restrict__ bout, float* __restrict__ feats) {
  int bs = blockIdx.x;
  int lane = threadIdx.x;
  const float* hp = h1 + (size_t)bs * 512;
  float hv[8];
  #pragma unroll
  for (int i = 0; i < 8; i++) hv[i] = hp[lane + i * 64];
  #pragma unroll
  for (int t = 0; t < TT; t++) {
    const float* wp = wout + t * 512;
    float p = 0.f;
    #pragma unroll
    for (int i = 0; i < 8; i++) p += hv[i] * wp[lane + i * 64];
    #pragma unroll
    for (int off = 32; off >= 1; off >>= 1) p += __shfl_down(p, off, 64);
    if (lane == 0) feats[(size_t)bs * TT + t] = p + bout[t];
  }
}

// ---------------- Viterbi decode ----------------
__global__ void viterbi_kernel(const float* __restrict__ feats, const float* __restrict__ trans,
                               float* __restrict__ out) {
  int b = blockIdx.x;
  int lane = threadIdx.x;
  __shared__ float tr[121];
  __shared__ float fch[32 * TT];
  __shared__ unsigned char bp[SS][12];
  __shared__ unsigned char path[SS];
  for (int i = lane; i < 121; i += 64) tr[i] = trans[i];
  __syncthreads();
  int ln = lane < TT ? lane : (TT - 1);
  float trr[TT];
  #pragma unroll
  for (int p = 0; p < TT; p++) trr[p] = tr[ln * TT + p];
  float fv = (lane == 9) ? 0.f : NEGV;   // START = 9
  const float* fb = feats + (size_t)b * SS * TT;

  for (int s = 0; s < SS; s++) {
    if ((s & 31) == 0) {
      __syncthreads();
      for (int i = lane; i < 32 * TT; i += 64) fch[i] = fb[s * TT + i];
      __syncthreads();
    }
    float best = -3.0e38f; int arg = 0;
    #pragma unroll
    for (int p = 0; p < TT; p++) {
      float v = __shfl(fv, p, 64) + trr[p];
      if (v > best) { best = v; arg = p; }   // strict > keeps FIRST max (numpy argmax)
    }
    if (lane < TT) bp[s][lane] = (unsigned char)arg;
    fv = best + fch[(s & 31) * TT + ln];
  }
  float term = fv + tr[10 * TT + ln];        // STOP = 10
  float best = -3.0e38f; int arg = 0;
  #pragma unroll
  for (int p = 0; p < TT; p++) {
    float v = __shfl(term, p, 64);
    if (v > best) { best = v; arg = p; }
  }
  __syncthreads();
  if (lane == 0) {
    out[b] = best;
    int tg = arg;
    path[SS - 1] = (unsigned char)tg;
    for (int s = SS - 1; s >= 1; s--) {
      tg = bp[s][tg];
      path[s - 1] = (unsigned char)tg;
    }
  }
  __syncthreads();
  for (int i = lane; i < SS; i += 64) out[32 + b * SS + i] = (float)path[i];
}

// ---------------- launcher ----------------
extern "C" void kernel_launch(void* const* d_in, const int* in_sizes, int n_in,
                              void* d_out, int out_size, void* d_ws, size_t ws_size,
                              hipStream_t stream) {
  const int*   x     = (const int*)d_in[0];
  const float* emb   = (const float*)d_in[2];
  const float* wih0f = (const float*)d_in[3];
  const float* whh0f = (const float*)d_in[4];
  const float* b0f   = (const float*)d_in[5];
  const float* wih0b = (const float*)d_in[6];
  const float* whh0b = (const float*)d_in[7];
  const float* b0b   = (const float*)d_in[8];
  const float* wih1f = (const float*)d_in[9];
  const float* whh1f = (const float*)d_in[10];
  const float* b1f   = (const float*)d_in[11];
  const float* wih1b = (const float*)d_in[12];
  const float* whh1b = (const float*)d_in[13];
  const float* b1b   = (const float*)d_in[14];
  const float* wout  = (const float*)d_in[15];
  const float* bout  = (const float*)d_in[16];
  const float* trans = (const float*)d_in[17];

  char* ws = (char*)d_ws;
  float* xe    = (float*)(ws + OFF_XE);
  float* xs    = (float*)(ws + OFF_XS);
  float* h0    = (float*)(ws + OFF_H0);
  float* h1    = (float*)(ws + OFF_H1);
  float* feats = (float*)(ws + OFF_FEATS);
  unsigned long long* hbuf8 = (unsigned long long*)(ws + OFF_HBUF);
  float* outp  = (float*)d_out;

  emb_kernel<<<4096, 256, 0, stream>>>(x, (const float4*)emb, (float4*)xe);
  proj_kernel<256><<<dim3(128, 8, 2), 256, 0, stream>>>(xe, wih0f, wih0b, b0f, b0b, xs);
  hipMemsetAsync(hbuf8, 0, 262144, stream);   // zero tagged h ping-pong (tag 0 == step 0)
  scan_kernel<<<dim3(64, 2), 256, 0, stream>>>(xs, whh0f, whh0b, hbuf8, h0);
  proj_kernel<512><<<dim3(128, 8, 2), 256, 0, stream>>>(h0, wih1f, wih1b, b1f, b1b, xs);
  hipMemsetAsync(hbuf8, 0, 262144, stream);
  scan_kernel<<<dim3(64, 2), 256, 0, stream>>>(xs, whh1f, whh1b, hbuf8, h1);
  feats_kernel<<<BB * SS, 64, 0, stream>>>(h1, wout, bout, feats);
  viterbi_kernel<<<BB, 64, 0, stream>>>(feats, trans, outp);
}

// Round 5
// 6552.453 us; speedup vs baseline: 1.9207x; 1.9207x over previous
//
#include <hip/hip_runtime.h>
#include <math.h>

#define SS 512
#define BB 32
#define HH 256
#define G4 1024
#define TT 11
#define NEGV (-1000.0f)

// ---------------- workspace layout (bytes) ----------------
static const size_t OFF_XE    = 0;                          // 16,777,216  : xe [B*S][256]
static const size_t OFF_XS    = 16777216ull;                // 134,217,728 : xs [2][S][B][1024]
static const size_t OFF_H0    = OFF_XS + 134217728ull;      // 33,554,432  : h0 [B*S][512]
static const size_t OFF_H1    = OFF_H0 + 33554432ull;       // 33,554,432  : h1 [B*S][512]
static const size_t OFF_FEATS = OFF_H1 + 33554432ull;       // 720,896     : feats [B][S][11]
static const size_t OFF_HBUF  = OFF_FEATS + 720896ull;      // 131,072     : h ping-pong [2 dir][2][B*256] f32
static const size_t OFF_FLG   = OFF_HBUF + 131072ull;       // 512         : flags [2][64]
// total ~219 MB

// fast transcendentals (1-2 ulp; outputs compared in bf16 w/ large threshold)
__device__ __forceinline__ float fsig(float x) {
  return __builtin_amdgcn_rcpf(1.f + __expf(-x));
}
__device__ __forceinline__ float ftanh(float x) {
  return 1.f - 2.f * __builtin_amdgcn_rcpf(__expf(2.f * x) + 1.f);
}

// ---------------- embedding gather ----------------
__global__ void emb_kernel(const int* __restrict__ x, const float4* __restrict__ emb,
                           float4* __restrict__ xe) {
  int idx = blockIdx.x * 256 + threadIdx.x;    // over B*S*H/4 = 1,048,576
  int bs  = idx >> 6;
  int kq  = idx & 63;
  int row = x[bs];
  xe[idx] = emb[(size_t)row * 64 + kq];
}

// ---------------- input projection GEMM ----------------
// C[m][n] = sum_k A[m][k]*W[n][k] + bias[n]  -> xs[dir][s][b][n], m = b*S+s
// 128x128 tile, 256 threads, 8x8 micro-tile, BK=8
template<int K>
__global__ __launch_bounds__(256, 2)
void proj_kernel(const float* __restrict__ A,
                 const float* __restrict__ Wf, const float* __restrict__ Wb,
                 const float* __restrict__ bf, const float* __restrict__ bb,
                 float* __restrict__ xs) {
  __shared__ float As[8][132];
  __shared__ float Bs[8][132];
  int tid = threadIdx.x;
  int dir = blockIdx.z;
  const float* W    = dir ? Wb : Wf;
  const float* bias = dir ? bb : bf;
  float* out = xs + (size_t)dir * (SS * BB * G4);
  int bm = blockIdx.x * 128;
  int bn = blockIdx.y * 128;
  int ty = tid >> 4;
  int tx = tid & 15;
  int lr = tid >> 1;
  int lk = (tid & 1) * 4;
  const float* Ap = A + (size_t)(bm + lr) * K + lk;
  const float* Wp = W + (size_t)(bn + lr) * K + lk;
  float acc[8][8];
  #pragma unroll
  for (int i = 0; i < 8; i++)
    #pragma unroll
    for (int j = 0; j < 8; j++) acc[i][j] = 0.f;

  for (int kt = 0; kt < K; kt += 8) {
    float4 av = *(const float4*)(Ap + kt);
    float4 bv = *(const float4*)(Wp + kt);
    __syncthreads();
    As[lk + 0][lr] = av.x; As[lk + 1][lr] = av.y; As[lk + 2][lr] = av.z; As[lk + 3][lr] = av.w;
    Bs[lk + 0][lr] = bv.x; Bs[lk + 1][lr] = bv.y; Bs[lk + 2][lr] = bv.z; Bs[lk + 3][lr] = bv.w;
    __syncthreads();
    #pragma unroll
    for (int k = 0; k < 8; k++) {
      float4 a0 = *(const float4*)&As[k][ty * 8];
      float4 a1 = *(const float4*)&As[k][ty * 8 + 4];
      float4 b0 = *(const float4*)&Bs[k][tx * 8];
      float4 b1 = *(const float4*)&Bs[k][tx * 8 + 4];
      float a[8] = {a0.x, a0.y, a0.z, a0.w, a1.x, a1.y, a1.z, a1.w};
      float b[8] = {b0.x, b0.y, b0.z, b0.w, b1.x, b1.y, b1.z, b1.w};
      #pragma unroll
      for (int i = 0; i < 8; i++)
        #pragma unroll
        for (int j = 0; j < 8; j++)
          acc[i][j] += a[i] * b[j];
    }
  }
  int nb = bn + tx * 8;
  float4 bias0 = *(const float4*)(bias + nb);
  float4 bias1 = *(const float4*)(bias + nb + 4);
  #pragma unroll
  for (int i = 0; i < 8; i++) {
    int gm = bm + ty * 8 + i;
    int b_ = gm >> 9;
    int s_ = gm & 511;
    float* op = out + (size_t)(s_ * BB + b_) * G4 + nb;
    float4 v0, v1;
    v0.x = acc[i][0] + bias0.x; v0.y = acc[i][1] + bias0.y;
    v0.z = acc[i][2] + bias0.z; v0.w = acc[i][3] + bias0.w;
    v1.x = acc[i][4] + bias1.x; v1.y = acc[i][5] + bias1.y;
    v1.z = acc[i][6] + bias1.z; v1.w = acc[i][7] + bias1.w;
    *(float4*)op = v0;
    *(float4*)(op + 4) = v1;
  }
}

// ---------------- recurrent scan (one bidirectional LSTM layer) ----------------
// grid (64, 2): blockIdx.x = cell-group (4 cells), blockIdx.y = direction.
// Flag protocol, minimal critical path:
//   - h via relaxed agent-scope atomics (L2-bypassing, coherent at MALL).
//   - ALL waves poll the 64-flag line independently (monotone flags).
//   - ONE __syncthreads per step (part-reduce).
//   - wave 0 alone updates cells, publishes h (8B paired stores), drains its
//     own vmcnt, stores the flag, THEN writes hout (off critical path).
//   - `part` LDS WAR across steps is protected by the flag protocol itself:
//     next-step partial writes require all flags >= s+1, which wave 0 only
//     publishes after reading `part`.
__global__ __launch_bounds__(256, 1)
void scan_kernel(const float* __restrict__ xs,      // [2][S][B][1024]
                 const float* __restrict__ whhf, const float* __restrict__ whhb,
                 float* __restrict__ hbuf,          // [2 dir][2 buf][32 b][256 col] f32
                 int* __restrict__ flg,             // [2][64]
                 float* __restrict__ hout)          // [B*S][512]
{
  int tid = threadIdx.x;
  int cb  = blockIdx.x;           // 0..63
  int dir = blockIdx.y;
  const float* whh = dir ? whhb : whhf;
  const float* xsd = xs + (size_t)dir * (SS * BB * G4);
  float* hb  = hbuf + (size_t)dir * (2 * BB * HH);
  int* myflg = flg + dir * 64;

  __shared__ float h_sh[32 * 260];       // h[b][k] padded: row stride 260 floats
  __shared__ float part[4 * 16 * 33];    // partial[w][row_local][b]

  int w    = tid >> 6;           // wave index = k-slice owner
  int lane = tid & 63;
  int r8   = lane >> 3;          // row pair: rows r8*2, r8*2+1
  int b8   = lane & 7;           // batches b8 + 8*jb
  int l5   = lane >> 5;          // batch half (staging)
  int j2   = lane & 31;          // col-pair within slice (staging)

  // preload weights into registers: wreg[i][j] = whh[grow(r8*2+i)][w*64 + j*4 ..+3]
  float4 wreg[2][16];
  #pragma unroll
  for (int i = 0; i < 2; i++) {
    int rl   = r8 * 2 + i;
    int grow = (rl >> 2) * 256 + cb * 4 + (rl & 3);
    const float* wp = whh + (size_t)grow * 256 + w * 64;
    #pragma unroll
    for (int j = 0; j < 16; j++) wreg[i][j] = *(const float4*)(wp + j * 4);
  }

  // wave-0 update role: lane -> batch ub, cells u0, u0+1
  int ub = lane & 31;
  int u0 = (lane >> 5) * 2;
  float c0 = 0.f, c1 = 0.f;
  float2* h_sh2 = (float2*)h_sh;

  // xs prefetch double-buffer (wave 0 only): xsn holds step-s gate pairs
  float2 xsn[4];
  if (w == 0) {
    int tpos0 = dir ? (SS - 1) : 0;
    const float* xp = xsd + ((size_t)(tpos0 * BB + ub) * G4) + cb * 4 + u0;
    #pragma unroll
    for (int g = 0; g < 4; g++) xsn[g] = *(const float2*)(xp + g * 256);
  }

  for (int s = 0; s < SS; ++s) {
    float2 xsg[4];
    if (w == 0) {
      #pragma unroll
      for (int g = 0; g < 4; g++) xsg[g] = xsn[g];
      if (s + 1 < SS) {                       // prefetch next step's xs
        int tposn = dir ? (SS - 2 - s) : (s + 1);
        const float* xp = xsd + ((size_t)(tposn * BB + ub) * G4) + cb * 4 + u0;
        #pragma unroll
        for (int g = 0; g < 4; g++) xsn[g] = *(const float2*)(xp + g * 256);
      }
    }

    // ---- poll: every wave independently waits for all 64 flags >= s ----
    for (;;) {
      int f = __hip_atomic_load(&myflg[lane], __ATOMIC_RELAXED, __HIP_MEMORY_SCOPE_AGENT);
      if (__all(f >= s)) break;
    }
    asm volatile("" ::: "memory");   // no hoisting of stage loads above the poll

    // ---- stage this wave's k-slice of h(prev): 32 batches x 2 cols/lane ----
    {
      const unsigned long long* hsrc8 =
          (const unsigned long long*)(hb + (size_t)(s & 1) * (BB * HH));
      unsigned long long hv8[16];
      #pragma unroll
      for (int i = 0; i < 16; i++) {
        int b_ = i * 2 + l5;
        hv8[i] = __hip_atomic_load(&hsrc8[b_ * 128 + w * 32 + j2],
                                   __ATOMIC_RELAXED, __HIP_MEMORY_SCOPE_AGENT);
      }
      #pragma unroll
      for (int i = 0; i < 16; i++) {
        int b_ = i * 2 + l5;
        float2 t; __builtin_memcpy(&t, &hv8[i], 8);
        h_sh2[b_ * 130 + w * 32 + j2] = t;
      }
    }
    // no cross-wave barrier: wave w wrote & reads only cols [w*64, w*64+64)

    // ---- partial dot products over this wave's k-slice ----
    float acc[2][4] = {{0.f,0.f,0.f,0.f},{0.f,0.f,0.f,0.f}};
    #pragma unroll
    for (int j = 0; j < 16; j++) {
      int k4 = w * 16 + j;
      float4 h0 = *(const float4*)&h_sh[(b8 +  0) * 260 + k4 * 4];
      float4 h1 = *(const float4*)&h_sh[(b8 +  8) * 260 + k4 * 4];
      float4 h2 = *(const float4*)&h_sh[(b8 + 16) * 260 + k4 * 4];
      float4 h3 = *(const float4*)&h_sh[(b8 + 24) * 260 + k4 * 4];
      #pragma unroll
      for (int i = 0; i < 2; i++) {
        float4 wv = wreg[i][j];
        acc[i][0] += wv.x * h0.x + wv.y * h0.y + wv.z * h0.z + wv.w * h0.w;
        acc[i][1] += wv.x * h1.x + wv.y * h1.y + wv.z * h1.z + wv.w * h1.w;
        acc[i][2] += wv.x * h2.x + wv.y * h2.y + wv.z * h2.z + wv.w * h2.w;
        acc[i][3] += wv.x * h3.x + wv.y * h3.y + wv.z * h3.z + wv.w * h3.w;
      }
    }
    #pragma unroll
    for (int i = 0; i < 2; i++) {
      int rl = r8 * 2 + i;
      #pragma unroll
      for (int jb = 0; jb < 4; jb++)
        part[(w * 16 + rl) * 33 + (b8 + 8 * jb)] = acc[i][jb];
    }
    __syncthreads();   // the ONLY barrier per step: partials -> wave-0 reduce

    // ---- wave 0: reduce + LSTM update + publish + flag + hout ----
    if (w == 0) {
      float gv[2][4];
      #pragma unroll
      for (int i = 0; i < 2; i++)
        #pragma unroll
        for (int g = 0; g < 4; g++) {
          int rl = g * 4 + u0 + i;
          float sum = (i == 0) ? xsg[g].x : xsg[g].y;
          #pragma unroll
          for (int ww = 0; ww < 4; ww++) sum += part[(ww * 16 + rl) * 33 + ub];
          gv[i][g] = sum;
        }
      float2 hp;
      {
        float ig = fsig(gv[0][0]), fg = fsig(gv[0][1]);
        float gg = ftanh(gv[0][2]), og = fsig(gv[0][3]);
        c0 = fg * c0 + ig * gg;
        hp.x = og * ftanh(c0);
      }
      {
        float ig = fsig(gv[1][0]), fg = fsig(gv[1][1]);
        float gg = ftanh(gv[1][2]), og = fsig(gv[1][3]);
        c1 = fg * c1 + ig * gg;
        hp.y = og * ftanh(c1);
      }
      // publish paired h (single 8B coherent store)
      unsigned long long pack; __builtin_memcpy(&pack, &hp, 8);
      unsigned long long* dst = (unsigned long long*)
          (hb + (size_t)((s + 1) & 1) * (BB * HH) + ub * HH + cb * 4 + u0);
      __hip_atomic_store(dst, pack, __ATOMIC_RELAXED, __HIP_MEMORY_SCOPE_AGENT);
      // drain THIS wave's h stores, then flag (no block barrier, no wbl2)
      asm volatile("s_waitcnt vmcnt(0)" ::: "memory");
      if (lane == 0)
        __hip_atomic_store(&myflg[cb], s + 1, __ATOMIC_RELAXED, __HIP_MEMORY_SCOPE_AGENT);
      // hout store AFTER the flag -> drains during next step's poll
      int tpos = dir ? (SS - 1 - s) : s;
      *(float2*)(hout + ((size_t)(ub * SS + tpos)) * 512 + dir * 256 + cb * 4 + u0) = hp;
    }
  }
}

// ---------------- emission features ----------------
__global__ void feats_kernel(const float* __restrict__ h1, const float* __restrict__ wout,
                             const float* __restrict__ bout, float* __restrict__ feats) {
  int bs = blockIdx.x;
  int lane = threadIdx.x;
  const float* hp = h1 + (size_t)bs * 512;
  float hv[8];
  #pragma unroll
  for (int i = 0; i < 8; i++) hv[i] = hp[lane + i * 64];
  #pragma unroll
  for (int t = 0; t < TT; t++) {
    const float* wp = wout + t * 512;
    float p = 0.f;
    #pragma unroll
    for (int i = 0; i < 8; i++) p += hv[i] * wp[lane + i * 64];
    #pragma unroll
    for (int off = 32; off >= 1; off >>= 1) p += __shfl_down(p, off, 64);
    if (lane == 0) feats[(size_t)bs * TT + t] = p + bout[t];
  }
}

// ---------------- Viterbi decode ----------------
__global__ void viterbi_kernel(const float* __restrict__ feats, const float* __restrict__ trans,
                               float* __restrict__ out) {
  int b = blockIdx.x;
  int lane = threadIdx.x;
  __shared__ float tr[121];
  __shared__ float fch[32 * TT];
  __shared__ unsigned char bp[SS][12];
  __shared__ unsigned char path[SS];
  for (int i = lane; i < 121; i += 64) tr[i] = trans[i];
  __syncthreads();
  int ln = lane < TT ? lane : (TT - 1);
  float trr[TT];
  #pragma unroll
  for (int p = 0; p < TT; p++) trr[p] = tr[ln * TT + p];
  float fv = (lane == 9) ? 0.f : NEGV;   // START = 9
  const float* fb = feats + (size_t)b * SS * TT;

  for (int s = 0; s < SS; s++) {
    if ((s & 31) == 0) {
      __syncthreads();
      for (int i = lane; i < 32 * TT; i += 64) fch[i] = fb[s * TT + i];
      __syncthreads();
    }
    float best = -3.0e38f; int arg = 0;
    #pragma unroll
    for (int p = 0; p < TT; p++) {
      float v = __shfl(fv, p, 64) + trr[p];
      if (v > best) { best = v; arg = p; }   // strict > keeps FIRST max (numpy argmax)
    }
    if (lane < TT) bp[s][lane] = (unsigned char)arg;
    fv = best + fch[(s & 31) * TT + ln];
  }
  float term = fv + tr[10 * TT + ln];        // STOP = 10
  float best = -3.0e38f; int arg = 0;
  #pragma unroll
  for (int p = 0; p < TT; p++) {
    float v = __shfl(term, p, 64);
    if (v > best) { best = v; arg = p; }
  }
  __syncthreads();
  if (lane == 0) {
    out[b] = best;
    int tg = arg;
    path[SS - 1] = (unsigned char)tg;
    for (int s = SS - 1; s >= 1; s--) {
      tg = bp[s][tg];
      path[s - 1] = (unsigned char)tg;
    }
  }
  __syncthreads();
  for (int i = lane; i < SS; i += 64) out[32 + b * SS + i] = (float)path[i];
}

// ---------------- launcher ----------------
extern "C" void kernel_launch(void* const* d_in, const int* in_sizes, int n_in,
                              void* d_out, int out_size, void* d_ws, size_t ws_size,
                              hipStream_t stream) {
  const int*   x     = (const int*)d_in[0];
  const float* emb   = (const float*)d_in[2];
  const float* wih0f = (const float*)d_in[3];
  const float* whh0f = (const float*)d_in[4];
  const float* b0f   = (const float*)d_in[5];
  const float* wih0b = (const float*)d_in[6];
  const float* whh0b = (const float*)d_in[7];
  const float* b0b   = (const float*)d_in[8];
  const float* wih1f = (const float*)d_in[9];
  const float* whh1f = (const float*)d_in[10];
  const float* b1f   = (const float*)d_in[11];
  const float* wih1b = (const float*)d_in[12];
  const float* whh1b = (const float*)d_in[13];
  const float* b1b   = (const float*)d_in[14];
  const float* wout  = (const float*)d_in[15];
  const float* bout  = (const float*)d_in[16];
  const float* trans = (const float*)d_in[17];

  char* ws = (char*)d_ws;
  float* xe    = (float*)(ws + OFF_XE);
  float* xs    = (float*)(ws + OFF_XS);
  float* h0    = (float*)(ws + OFF_H0);
  float* h1    = (float*)(ws + OFF_H1);
  float* feats = (float*)(ws + OFF_FEATS);
  float* hbuf  = (float*)(ws + OFF_HBUF);
  int*   flg   = (int*)(ws + OFF_FLG);
  float* outp  = (float*)d_out;

  emb_kernel<<<4096, 256, 0, stream>>>(x, (const float4*)emb, (float4*)xe);
  proj_kernel<256><<<dim3(128, 8, 2), 256, 0, stream>>>(xe, wih0f, wih0b, b0f, b0b, xs);
  hipMemsetAsync(hbuf, 0, 131072 + 512, stream);   // zero h ping-pong + flags
  scan_kernel<<<dim3(64, 2), 256, 0, stream>>>(xs, whh0f, whh0b, hbuf, flg, h0);
  proj_kernel<512><<<dim3(128, 8, 2), 256, 0, stream>>>(h0, wih1f, wih1b, b1f, b1b, xs);
  hipMemsetAsync(hbuf, 0, 131072 + 512, stream);
  scan_kernel<<<dim3(64, 2), 256, 0, stream>>>(xs, whh1f, whh1b, hbuf, flg, h1);
  feats_kernel<<<BB * SS, 64, 0, stream>>>(h1, wout, bout, feats);
  viterbi_kernel<<<BB, 64, 0, stream>>>(feats, trans, outp);
}

// Round 6
// 3848.440 us; speedup vs baseline: 3.2702x; 1.7026x over previous
//
#include <hip/hip_runtime.h>
#include <math.h>

#define SS 512
#define BB 32
#define HH 256
#define G4 1024
#define TT 11
#define NEGV (-1000.0f)

// ---------------- workspace layout (bytes) ----------------
static const size_t OFF_XE    = 0;                          // 16,777,216  : xe [B*S][256]
static const size_t OFF_XS    = 16777216ull;                // 134,217,728 : xs [2][S][B][1024]
static const size_t OFF_H0    = OFF_XS + 134217728ull;      // 33,554,432  : h0 [B*S][512]
static const size_t OFF_H1    = OFF_H0 + 33554432ull;       // 33,554,432  : h1 [B*S][512]
static const size_t OFF_FEATS = OFF_H1 + 33554432ull;       // 720,896     : feats [B][S][11]
static const size_t OFF_HGRP  = OFF_FEATS + 720896ull;      // 1,048,576   : tagged h [2 dir][8 g][2 buf][4 b][256] u64
// total ~220 MB

// fast transcendentals (1-2 ulp; outputs compared in bf16 w/ large threshold)
__device__ __forceinline__ float fsig(float x) {
  return __builtin_amdgcn_rcpf(1.f + __expf(-x));
}
__device__ __forceinline__ float ftanh(float x) {
  return 1.f - 2.f * __builtin_amdgcn_rcpf(__expf(2.f * x) + 1.f);
}

// raw barrier: drains LDS ops only (NO vmcnt(0) drain -> store acks / in-flight
// loads never block the barrier, unlike __syncthreads)
__device__ __forceinline__ void block_sync_lds() {
  asm volatile("s_waitcnt lgkmcnt(0)\n\ts_barrier" ::: "memory");
}

// ---------------- embedding gather ----------------
__global__ void emb_kernel(const int* __restrict__ x, const float4* __restrict__ emb,
                           float4* __restrict__ xe) {
  int idx = blockIdx.x * 256 + threadIdx.x;    // over B*S*H/4 = 1,048,576
  int bs  = idx >> 6;
  int kq  = idx & 63;
  int row = x[bs];
  xe[idx] = emb[(size_t)row * 64 + kq];
}

// ---------------- input projection GEMM ----------------
// C[m][n] = sum_k A[m][k]*W[n][k] + bias[n]  -> xs[dir][s][b][n], m = b*S+s
// 128x128 tile, 256 threads, 8x8 micro-tile, BK=8
template<int K>
__global__ __launch_bounds__(256, 2)
void proj_kernel(const float* __restrict__ A,
                 const float* __restrict__ Wf, const float* __restrict__ Wb,
                 const float* __restrict__ bf, const float* __restrict__ bb,
                 float* __restrict__ xs) {
  __shared__ float As[8][132];
  __shared__ float Bs[8][132];
  int tid = threadIdx.x;
  int dir = blockIdx.z;
  const float* W    = dir ? Wb : Wf;
  const float* bias = dir ? bb : bf;
  float* out = xs + (size_t)dir * (SS * BB * G4);
  int bm = blockIdx.x * 128;
  int bn = blockIdx.y * 128;
  int ty = tid >> 4;
  int tx = tid & 15;
  int lr = tid >> 1;
  int lk = (tid & 1) * 4;
  const float* Ap = A + (size_t)(bm + lr) * K + lk;
  const float* Wp = W + (size_t)(bn + lr) * K + lk;
  float acc[8][8];
  #pragma unroll
  for (int i = 0; i < 8; i++)
    #pragma unroll
    for (int j = 0; j < 8; j++) acc[i][j] = 0.f;

  for (int kt = 0; kt < K; kt += 8) {
    float4 av = *(const float4*)(Ap + kt);
    float4 bv = *(const float4*)(Wp + kt);
    __syncthreads();
    As[lk + 0][lr] = av.x; As[lk + 1][lr] = av.y; As[lk + 2][lr] = av.z; As[lk + 3][lr] = av.w;
    Bs[lk + 0][lr] = bv.x; Bs[lk + 1][lr] = bv.y; Bs[lk + 2][lr] = bv.z; Bs[lk + 3][lr] = bv.w;
    __syncthreads();
    #pragma unroll
    for (int k = 0; k < 8; k++) {
      float4 a0 = *(const float4*)&As[k][ty * 8];
      float4 a1 = *(const float4*)&As[k][ty * 8 + 4];
      float4 b0 = *(const float4*)&Bs[k][tx * 8];
      float4 b1 = *(const float4*)&Bs[k][tx * 8 + 4];
      float a[8] = {a0.x, a0.y, a0.z, a0.w, a1.x, a1.y, a1.z, a1.w};
      float b[8] = {b0.x, b0.y, b0.z, b0.w, b1.x, b1.y, b1.z, b1.w};
      #pragma unroll
      for (int i = 0; i < 8; i++)
        #pragma unroll
        for (int j = 0; j < 8; j++)
          acc[i][j] += a[i] * b[j];
    }
  }
  int nb = bn + tx * 8;
  float4 bias0 = *(const float4*)(bias + nb);
  float4 bias1 = *(const float4*)(bias + nb + 4);
  #pragma unroll
  for (int i = 0; i < 8; i++) {
    int gm = bm + ty * 8 + i;
    int b_ = gm >> 9;
    int s_ = gm & 511;
    float* op = out + (size_t)(s_ * BB + b_) * G4 + nb;
    float4 v0, v1;
    v0.x = acc[i][0] + bias0.x; v0.y = acc[i][1] + bias0.y;
    v0.z = acc[i][2] + bias0.z; v0.w = acc[i][3] + bias0.w;
    v1.x = acc[i][4] + bias1.x; v1.y = acc[i][5] + bias1.y;
    v1.z = acc[i][6] + bias1.z; v1.w = acc[i][7] + bias1.w;
    *(float4*)op = v0;
    *(float4*)(op + 4) = v1;
  }
}

// ---------------- recurrent scan (one bidirectional LSTM layer) ----------------
// grid (8 cg, 8 g, 2 dir) x 320 threads.
// Block = cells [cg*32, cg*32+32) x batches [g*4, g*4+4) x direction dir.
// The recurrence is independent per batch -> only the 8 blocks of a (dir,g)
// group exchange h, via a dense TAGGED region hg[2 buf][4 b][256 col] of
// u64 = (step_tag<<32)|f32. The consumer's poll load IS the data read: one
// MALL round trip producer->consumer, no flags, no fences, no vmcnt drains.
// Waves 0-3: pure GEMM (poll+stage k-slice [w*64,w*64+64), dot, partials).
//   Their ONLY vmem is the poll load -> clean FIFO, poll never waits acks.
// Wave 4: reduce+LSTM update (owns c-state), publish tagged h, hout, xs
//   prefetch. It never polls -> its store acks never block anything.
// One lgkm-only barrier per step. `part` is ping-ponged; cross-step WAR is
// covered transitively by the group tag chain (publish s+1 happens after
// reading part[s&1]; any step-s+2 activity implies all s+1 publishes seen).
__global__ __launch_bounds__(320, 2)
void scan_kernel(const float* __restrict__ xs,      // [2][S][B][1024]
                 const float* __restrict__ whhf, const float* __restrict__ whhb,
                 unsigned long long* __restrict__ hgrp,  // [2][8][2][4][256] u64
                 float* __restrict__ hout)          // [B*S][512]
{
  int tid  = threadIdx.x;
  int w    = tid >> 6;          // wave 0..4
  int lane = tid & 63;
  int cg   = blockIdx.x;        // cell group 0..7
  int g    = blockIdx.y;        // batch group 0..7
  int dir  = blockIdx.z;
  const float* xsd = xs + (size_t)dir * (SS * BB * G4);
  unsigned long long* hg = hgrp + (size_t)(dir * 8 + g) * (2 * 4 * 256);

  __shared__ float h_sh[4][256];            // [local b][col], per-wave slices
  __shared__ float part[2][4][4][4][32];    // [buf][w][b][gate][c]

  int c  = lane & 31;
  int bp = lane >> 5;

  if (w < 4) {
    // ---------------- GEMM waves ----------------
    const float* whh = dir ? whhb : whhf;
    int i0 = bp * 2;                        // gates {i0, i0+1}
    float4 wreg[2][16];                     // whh[gate row][k-slice w]
    #pragma unroll
    for (int i = 0; i < 2; i++) {
      int grow = (i0 + i) * 256 + cg * 32 + c;
      const float* wp = whh + (size_t)grow * 256 + w * 64;
      #pragma unroll
      for (int j = 0; j < 16; j++) wreg[i][j] = *(const float4*)(wp + j * 4);
    }
    int col = w * 64 + lane;                // staged column (global 0..255)

    for (int s = 0; s < SS; ++s) {
      // ---- poll+stage: 4 tagged words (4 local batches) ----
      const unsigned long long* src = hg + (size_t)(s & 1) * 1024 + col;
      unsigned long long rv0, rv1, rv2, rv3;
      for (;;) {
        rv0 = __hip_atomic_load(src,       __ATOMIC_RELAXED, __HIP_MEMORY_SCOPE_AGENT);
        rv1 = __hip_atomic_load(src + 256, __ATOMIC_RELAXED, __HIP_MEMORY_SCOPE_AGENT);
        rv2 = __hip_atomic_load(src + 512, __ATOMIC_RELAXED, __HIP_MEMORY_SCOPE_AGENT);
        rv3 = __hip_atomic_load(src + 768, __ATOMIC_RELAXED, __HIP_MEMORY_SCOPE_AGENT);
        unsigned t = ((unsigned)(rv0 >> 32) ^ (unsigned)s) |
                     ((unsigned)(rv1 >> 32) ^ (unsigned)s) |
                     ((unsigned)(rv2 >> 32) ^ (unsigned)s) |
                     ((unsigned)(rv3 >> 32) ^ (unsigned)s);
        if (__all(t == 0u)) break;
      }
      {
        unsigned l0 = (unsigned)rv0, l1 = (unsigned)rv1,
                 l2 = (unsigned)rv2, l3 = (unsigned)rv3;
        float f0, f1, f2, f3;
        __builtin_memcpy(&f0, &l0, 4); __builtin_memcpy(&f1, &l1, 4);
        __builtin_memcpy(&f2, &l2, 4); __builtin_memcpy(&f3, &l3, 4);
        h_sh[0][col] = f0; h_sh[1][col] = f1;
        h_sh[2][col] = f2; h_sh[3][col] = f3;
      }

      // ---- dots over this wave's k-slice (broadcast LDS reads, free) ----
      float acc[2][4] = {{0.f,0.f,0.f,0.f},{0.f,0.f,0.f,0.f}};
      #pragma unroll
      for (int j = 0; j < 16; j++) {
        int k4 = w * 64 + j * 4;
        float4 hb0 = *(const float4*)&h_sh[0][k4];
        float4 hb1 = *(const float4*)&h_sh[1][k4];
        float4 hb2 = *(const float4*)&h_sh[2][k4];
        float4 hb3 = *(const float4*)&h_sh[3][k4];
        #pragma unroll
        for (int i = 0; i < 2; i++) {
          float4 wv = wreg[i][j];
          acc[i][0] += wv.x * hb0.x + wv.y * hb0.y + wv.z * hb0.z + wv.w * hb0.w;
          acc[i][1] += wv.x * hb1.x + wv.y * hb1.y + wv.z * hb1.z + wv.w * hb1.w;
          acc[i][2] += wv.x * hb2.x + wv.y * hb2.y + wv.z * hb2.z + wv.w * hb2.w;
          acc[i][3] += wv.x * hb3.x + wv.y * hb3.y + wv.z * hb3.z + wv.w * hb3.w;
        }
      }
      #pragma unroll
      for (int i = 0; i < 2; i++)
        #pragma unroll
        for (int b = 0; b < 4; b++)
          part[s & 1][w][b][i0 + i][c] = acc[i][b];

      block_sync_lds();
    }
  } else {
    // ---------------- wave 4: update / publish / hout / xs ----------------
    int b0l = bp * 2;                       // local batches b0l, b0l+1
    int gb0 = g * 4 + b0l, gb1 = gb0 + 1;   // global batches
    int colp = cg * 32 + c;                 // this lane's cell column
    float c0 = 0.f, c1 = 0.f;
    float xg0[4], xg1[4];
    {
      int tpos = dir ? (SS - 1) : 0;
      const float* xp0 = xsd + (size_t)(tpos * BB + gb0) * G4 + colp;
      const float* xp1 = xsd + (size_t)(tpos * BB + gb1) * G4 + colp;
      #pragma unroll
      for (int i = 0; i < 4; i++) { xg0[i] = xp0[i * 256]; xg1[i] = xp1[i * 256]; }
    }

    for (int s = 0; s < SS; ++s) {
      block_sync_lds();                     // partials for step s are ready

      float gv0[4], gv1[4];
      #pragma unroll
      for (int i = 0; i < 4; i++) {
        float s0 = xg0[i], s1 = xg1[i];
        #pragma unroll
        for (int ww = 0; ww < 4; ww++) {
          s0 += part[s & 1][ww][b0l][i][c];
          s1 += part[s & 1][ww][b0l + 1][i][c];
        }
        gv0[i] = s0; gv1[i] = s1;
      }
      float hv0, hv1;
      { float ig = fsig(gv0[0]), fg = fsig(gv0[1]);
        float gg = ftanh(gv0[2]), og = fsig(gv0[3]);
        c0 = fg * c0 + ig * gg; hv0 = og * ftanh(c0); }
      { float ig = fsig(gv1[0]), fg = fsig(gv1[1]);
        float gg = ftanh(gv1[2]), og = fsig(gv1[3]);
        c1 = fg * c1 + ig * gg; hv1 = og * ftanh(c1); }

      // publish tagged h for step s+1 (self-flagging; no drain needed)
      unsigned hb0, hb1;
      __builtin_memcpy(&hb0, &hv0, 4); __builtin_memcpy(&hb1, &hv1, 4);
      unsigned long long tagw = (unsigned long long)(unsigned)(s + 1) << 32;
      unsigned long long* dst = hg + (size_t)((s + 1) & 1) * 1024 + colp;
      __hip_atomic_store(dst + (size_t)b0l * 256,      tagw | hb0,
                         __ATOMIC_RELAXED, __HIP_MEMORY_SCOPE_AGENT);
      __hip_atomic_store(dst + (size_t)(b0l + 1) * 256, tagw | hb1,
                         __ATOMIC_RELAXED, __HIP_MEMORY_SCOPE_AGENT);

      // hout (full 128B-line segments; acks never waited on)
      int tpos = dir ? (SS - 1 - s) : s;
      hout[((size_t)(gb0 * SS + tpos)) * 512 + dir * 256 + colp] = hv0;
      hout[((size_t)(gb1 * SS + tpos)) * 512 + dir * 256 + colp] = hv1;

      // prefetch next step's xs (consumed a full step later -> latency hidden)
      if (s + 1 < SS) {
        int tpn = dir ? (SS - 2 - s) : (s + 1);
        const float* xp0 = xsd + (size_t)(tpn * BB + gb0) * G4 + colp;
        const float* xp1 = xsd + (size_t)(tpn * BB + gb1) * G4 + colp;
        #pragma unroll
        for (int i = 0; i < 4; i++) { xg0[i] = xp0[i * 256]; xg1[i] = xp1[i * 256]; }
      }
    }
  }
}

// ---------------- emission features ----------------
__global__ void feats_kernel(const float* __restrict__ h1, const float* __restrict__ wout,
                             const float* __restrict__ bout, float* __restrict__ feats) {
  int bs = blockIdx.x;
  int lane = threadIdx.x;
  const float* hp = h1 + (size_t)bs * 512;
  float hv[8];
  #pragma unroll
  for (int i = 0; i < 8; i++) hv[i] = hp[lane + i * 64];
  #pragma unroll
  for (int t = 0; t < TT; t++) {
    const float* wp = wout + t * 512;
    float p = 0.f;
    #pragma unroll
    for (int i = 0; i < 8; i++) p += hv[i] * wp[lane + i * 64];
    #pragma unroll
    for (int off = 32; off >= 1; off >>= 1) p += __shfl_down(p, off, 64);
    if (lane == 0) feats[(size_t)bs * TT + t] = p + bout[t];
  }
}

// ---------------- Viterbi decode ----------------
__global__ void viterbi_kernel(const float* __restrict__ feats, const float* __restrict__ trans,
                               float* __restrict__ out) {
  int b = blockIdx.x;
  int lane = threadIdx.x;
  __shared__ float tr[121];
  __shared__ float fch[32 * TT];
  __shared__ unsigned char bp[SS][12];
  __shared__ unsigned char path[SS];
  for (int i = lane; i < 121; i += 64) tr[i] = trans[i];
  __syncthreads();
  int ln = lane < TT ? lane : (TT - 1);
  float trr[TT];
  #pragma unroll
  for (int p = 0; p < TT; p++) trr[p] = tr[ln * TT + p];
  float fv = (lane == 9) ? 0.f : NEGV;   // START = 9
  const float* fb = feats + (size_t)b * SS * TT;

  for (int s = 0; s < SS; s++) {
    if ((s & 31) == 0) {
      __syncthreads();
      for (int i = lane; i < 32 * TT; i += 64) fch[i] = fb[s * TT + i];
      __syncthreads();
    }
    float best = -3.0e38f; int arg = 0;
    #pragma unroll
    for (int p = 0; p < TT; p++) {
      float v = __shfl(fv, p, 64) + trr[p];
      if (v > best) { best = v; arg = p; }   // strict > keeps FIRST max (numpy argmax)
    }
    if (lane < TT) bp[s][lane] = (unsigned char)arg;
    fv = best + fch[(s & 31) * TT + ln];
  }
  float term = fv + tr[10 * TT + ln];        // STOP = 10
  float best = -3.0e38f; int arg = 0;
  #pragma unroll
  for (int p = 0; p < TT; p++) {
    float v = __shfl(term, p, 64);
    if (v > best) { best = v; arg = p; }
  }
  __syncthreads();
  if (lane == 0) {
    out[b] = best;
    int tg = arg;
    path[SS - 1] = (unsigned char)tg;
    for (int s = SS - 1; s >= 1; s--) {
      tg = bp[s][tg];
      path[s - 1] = (unsigned char)tg;
    }
  }
  __syncthreads();
  for (int i = lane; i < SS; i += 64) out[32 + b * SS + i] = (float)path[i];
}

// ---------------- launcher ----------------
extern "C" void kernel_launch(void* const* d_in, const int* in_sizes, int n_in,
                              void* d_out, int out_size, void* d_ws, size_t ws_size,
                              hipStream_t stream) {
  const int*   x     = (const int*)d_in[0];
  const float* emb   = (const float*)d_in[2];
  const float* wih0f = (const float*)d_in[3];
  const float* whh0f = (const float*)d_in[4];
  const float* b0f   = (const float*)d_in[5];
  const float* wih0b = (const float*)d_in[6];
  const float* whh0b = (const float*)d_in[7];
  const float* b0b   = (const float*)d_in[8];
  const float* wih1f = (const float*)d_in[9];
  const float* whh1f = (const float*)d_in[10];
  const float* b1f   = (const float*)d_in[11];
  const float* wih1b = (const float*)d_in[12];
  const float* whh1b = (const float*)d_in[13];
  const float* b1b   = (const float*)d_in[14];
  const float* wout  = (const float*)d_in[15];
  const float* bout  = (const float*)d_in[16];
  const float* trans = (const float*)d_in[17];

  char* ws = (char*)d_ws;
  float* xe    = (float*)(ws + OFF_XE);
  float* xs    = (float*)(ws + OFF_XS);
  float* h0    = (float*)(ws + OFF_H0);
  float* h1    = (float*)(ws + OFF_H1);
  float* feats = (float*)(ws + OFF_FEATS);
  unsigned long long* hgrp = (unsigned long long*)(ws + OFF_HGRP);
  float* outp  = (float*)d_out;

  emb_kernel<<<4096, 256, 0, stream>>>(x, (const float4*)emb, (float4*)xe);
  proj_kernel<256><<<dim3(128, 8, 2), 256, 0, stream>>>(xe, wih0f, wih0b, b0f, b0b, xs);
  hipMemsetAsync(hgrp, 0, 1048576, stream);   // tag 0 == initial h(0) = 0
  scan_kernel<<<dim3(8, 8, 2), 320, 0, stream>>>(xs, whh0f, whh0b, hgrp, h0);
  proj_kernel<512><<<dim3(128, 8, 2), 256, 0, stream>>>(h0, wih1f, wih1b, b1f, b1b, xs);
  hipMemsetAsync(hgrp, 0, 1048576, stream);
  scan_kernel<<<dim3(8, 8, 2), 320, 0, stream>>>(xs, whh1f, whh1b, hgrp, h1);
  feats_kernel<<<BB * SS, 64, 0, stream>>>(h1, wout, bout, feats);
  viterbi_kernel<<<BB, 64, 0, stream>>>(feats, trans, outp);
}

// Round 8
// 3489.489 us; speedup vs baseline: 3.6066x; 1.1029x over previous
//
#include <hip/hip_runtime.h>
#include <math.h>

#define SS 512
#define BB 32
#define HH 256
#define G4 1024
#define TT 11
#define NEGV (-1000.0f)

// ---------------- workspace layout (bytes) ----------------
static const size_t OFF_XEH   = 0;                          // 8,388,608  : xe_hi [16384][256] bf16
static const size_t OFF_XEL   = 8388608ull;                 // 8,388,608  : xe_lo
static const size_t OFF_XS    = 16777216ull;                // 134,217,728: xs [2][S][B][1024] f32
static const size_t OFF_H0    = OFF_XS + 134217728ull;      // 33,554,432 : h0 [B*S][512] f32
static const size_t OFF_H1    = OFF_H0 + 33554432ull;       // 33,554,432 : h1 f32 (also h0_hi/h0_lo bf16 before scan1)
static const size_t OFF_FEATS = OFF_H1 + 33554432ull;       // 720,896    : feats [B][S][11]
static const size_t OFF_HGRP  = OFF_FEATS + 720896ull;      // 1,048,576  : tagged h [2][8][2][4][256] u64
static const size_t OFF_W0H   = OFF_HGRP + 1048576ull;      // 1,048,576  : wih0 hi [2][1024][256] bf16
static const size_t OFF_W0L   = OFF_W0H + 1048576ull;       // 1,048,576
static const size_t OFF_W1H   = OFF_W0L + 1048576ull;       // 2,097,152  : wih1 hi [2][1024][512] bf16
static const size_t OFF_W1L   = OFF_W1H + 2097152ull;       // 2,097,152
// total ~226 MB

typedef __attribute__((ext_vector_type(8))) short short8;
typedef __attribute__((ext_vector_type(4))) float f32x4;

// fast transcendentals (1-2 ulp; outputs compared in bf16 w/ large threshold)
__device__ __forceinline__ float fsig(float x) {
  return __builtin_amdgcn_rcpf(1.f + __expf(-x));
}
__device__ __forceinline__ float ftanh(float x) {
  return 1.f - 2.f * __builtin_amdgcn_rcpf(__expf(2.f * x) + 1.f);
}

// raw barrier: drains LDS ops only (NO vmcnt(0) drain)
__device__ __forceinline__ void block_sync_lds() {
  asm volatile("s_waitcnt lgkmcnt(0)\n\ts_barrier" ::: "memory");
}

// ---------------- bf16 hi/lo split helpers ----------------
__device__ __forceinline__ unsigned short bfh(float x) {
  unsigned u = __float_as_uint(x);
  unsigned r = u + 0x7fffu + ((u >> 16) & 1u);   // RNE to bf16 (finite inputs)
  return (unsigned short)(r >> 16);
}
__device__ __forceinline__ void split1(float x, unsigned short& h, unsigned short& l) {
  h = bfh(x);
  float hf = __uint_as_float(((unsigned)h) << 16);
  l = bfh(x - hf);
}

// ---------------- embedding gather + split ----------------
__global__ void emb_kernel(const int* __restrict__ x, const float4* __restrict__ emb,
                           ushort4* __restrict__ xeh, ushort4* __restrict__ xel) {
  int idx = blockIdx.x * 256 + threadIdx.x;    // over B*S*64 float4-chunks
  int bs  = idx >> 6;
  int kq  = idx & 63;
  float4 v = emb[(size_t)x[bs] * 64 + kq];
  ushort4 h, l;
  split1(v.x, h.x, l.x); split1(v.y, h.y, l.y);
  split1(v.z, h.z, l.z); split1(v.w, h.w, l.w);
  xeh[idx] = h; xel[idx] = l;
}

// ---------------- generic f32 -> bf16 hi/lo split ----------------
__global__ void split_kernel(const float4* __restrict__ in, ushort4* __restrict__ oh,
                             ushort4* __restrict__ ol, int n4) {
  int i = blockIdx.x * 256 + threadIdx.x;
  if (i < n4) {
    float4 v = in[i];
    ushort4 h, l;
    split1(v.x, h.x, l.x); split1(v.y, h.y, l.y);
    split1(v.z, h.z, l.z); split1(v.w, h.w, l.w);
    oh[i] = h; ol[i] = l;
  }
}

// ---------------- input projection GEMM via split-bf16 MFMA ----------------
// C[m][n] = sum_k A[m][k]*W[n][k] + bias[n], computed as (Ah+Al)(Wh+Wl) with
// 4 bf16 MFMA products (hh+hl+lh+ll), fp32 accumulate -> ~2^-18 rel error.
// Block tile 64m x 128n, 4 waves (2x2), wave tile 32m x 64n = 2x4 MFMA tiles.
// mfma_f32_16x16x32_bf16: A/B frag = 8 bf16 (lane&15 = m/n, k = quad*8+j);
// C/D: col=lane&15, row=quad*4+reg  [verified m89/m91].
// R8 FIX: stage the FULL 32-short K-slab per row (R7 staged only 16 shorts ->
// uninitialized LDS garbage in shorts 16..31 -> absmax 3e38).
template<int K>
__global__ __launch_bounds__(256, 2)
void proj_mfma(const unsigned short* __restrict__ Ah_g, const unsigned short* __restrict__ Al_g,
               const unsigned short* __restrict__ Wh_g, const unsigned short* __restrict__ Wl_g,
               const float* __restrict__ bf, const float* __restrict__ bb,
               float* __restrict__ xs) {
  int tid = threadIdx.x;
  int bm  = blockIdx.x * 64;
  int bn  = blockIdx.y * 128;
  int dir = blockIdx.z;
  const unsigned short* Wh = Wh_g + (size_t)dir * 1024 * K;
  const unsigned short* Wl = Wl_g + (size_t)dir * 1024 * K;
  const float* bias = dir ? bb : bf;
  float* out = xs + (size_t)dir * (SS * BB * G4);

  // rows padded to 40 shorts (80 B): frag reads land 2-way max on banks (free)
  __shared__ unsigned short AhS[64][40], AlS[64][40];
  __shared__ unsigned short BhS[128][40], BlS[128][40];

  int w = tid >> 6, lane = tid & 63;
  int wm = w >> 1, wn = w & 1;
  int fr = lane & 15, q8 = (lane >> 4) * 8;
  int ra = tid >> 2;                 // staging row 0..63
  int ck = (tid & 3) * 8;            // staging chunk: 4 x 8 shorts = 32 shorts/row

  f32x4 acc[2][4];
  #pragma unroll
  for (int mt = 0; mt < 2; mt++)
    #pragma unroll
    for (int nt = 0; nt < 4; nt++) acc[mt][nt] = 0;

  for (int k0 = 0; k0 < K; k0 += 32) {
    __syncthreads();
    // A: 64 rows x 32 shorts (1 uint4 store/thread per matrix)
    *(uint4*)&AhS[ra][ck] = *(const uint4*)(Ah_g + (size_t)(bm + ra) * K + k0 + ck);
    *(uint4*)&AlS[ra][ck] = *(const uint4*)(Al_g + (size_t)(bm + ra) * K + k0 + ck);
    // B: 128 rows x 32 shorts (2 uint4 stores/thread per matrix)
    *(uint4*)&BhS[ra][ck]      = *(const uint4*)(Wh + (size_t)(bn + ra) * K + k0 + ck);
    *(uint4*)&BhS[ra + 64][ck] = *(const uint4*)(Wh + (size_t)(bn + ra + 64) * K + k0 + ck);
    *(uint4*)&BlS[ra][ck]      = *(const uint4*)(Wl + (size_t)(bn + ra) * K + k0 + ck);
    *(uint4*)&BlS[ra + 64][ck] = *(const uint4*)(Wl + (size_t)(bn + ra + 64) * K + k0 + ck);
    __syncthreads();

    short8 ah[2], al[2], bh[4], bl[4];
    #pragma unroll
    for (int mt = 0; mt < 2; mt++) {
      ah[mt] = *(const short8*)&AhS[wm * 32 + mt * 16 + fr][q8];
      al[mt] = *(const short8*)&AlS[wm * 32 + mt * 16 + fr][q8];
    }
    #pragma unroll
    for (int nt = 0; nt < 4; nt++) {
      bh[nt] = *(const short8*)&BhS[wn * 64 + nt * 16 + fr][q8];
      bl[nt] = *(const short8*)&BlS[wn * 64 + nt * 16 + fr][q8];
    }
    #pragma unroll
    for (int mt = 0; mt < 2; mt++)
      #pragma unroll
      for (int nt = 0; nt < 4; nt++) {
        acc[mt][nt] = __builtin_amdgcn_mfma_f32_16x16x32_bf16(ah[mt], bh[nt], acc[mt][nt], 0, 0, 0);
        acc[mt][nt] = __builtin_amdgcn_mfma_f32_16x16x32_bf16(ah[mt], bl[nt], acc[mt][nt], 0, 0, 0);
        acc[mt][nt] = __builtin_amdgcn_mfma_f32_16x16x32_bf16(al[mt], bh[nt], acc[mt][nt], 0, 0, 0);
        acc[mt][nt] = __builtin_amdgcn_mfma_f32_16x16x32_bf16(al[mt], bl[nt], acc[mt][nt], 0, 0, 0);
      }
  }

  // epilogue: C/D col = lane&15 (n), row = quad*4+reg (m); out[(s*B+b)*1024+n]
  #pragma unroll
  for (int mt = 0; mt < 2; mt++)
    #pragma unroll
    for (int nt = 0; nt < 4; nt++) {
      int n  = bn + wn * 64 + nt * 16 + fr;
      float bv = bias[n];
      int mbase = bm + wm * 32 + mt * 16 + (lane >> 4) * 4;
      #pragma unroll
      for (int r = 0; r < 4; r++) {
        int mm = mbase + r;
        int b_ = mm >> 9;
        int s_ = mm & 511;
        out[(size_t)(s_ * BB + b_) * G4 + n] = acc[mt][nt][r] + bv;
      }
    }
}

// ---------------- recurrent scan (UNCHANGED from R6 -- verified) ----------------
__global__ __launch_bounds__(320, 2)
void scan_kernel(const float* __restrict__ xs,      // [2][S][B][1024]
                 const float* __restrict__ whhf, const float* __restrict__ whhb,
                 unsigned long long* __restrict__ hgrp,  // [2][8][2][4][256] u64
                 float* __restrict__ hout)          // [B*S][512]
{
  int tid  = threadIdx.x;
  int w    = tid >> 6;          // wave 0..4
  int lane = tid & 63;
  int cg   = blockIdx.x;        // cell group 0..7
  int g    = blockIdx.y;        // batch group 0..7
  int dir  = blockIdx.z;
  const float* xsd = xs + (size_t)dir * (SS * BB * G4);
  unsigned long long* hg = hgrp + (size_t)(dir * 8 + g) * (2 * 4 * 256);

  __shared__ float h_sh[4][256];            // [local b][col], per-wave slices
  __shared__ float part[2][4][4][4][32];    // [buf][w][b][gate][c]

  int c  = lane & 31;
  int bp = lane >> 5;

  if (w < 4) {
    const float* whh = dir ? whhb : whhf;
    int i0 = bp * 2;                        // gates {i0, i0+1}
    float4 wreg[2][16];
    #pragma unroll
    for (int i = 0; i < 2; i++) {
      int grow = (i0 + i) * 256 + cg * 32 + c;
      const float* wp = whh + (size_t)grow * 256 + w * 64;
      #pragma unroll
      for (int j = 0; j < 16; j++) wreg[i][j] = *(const float4*)(wp + j * 4);
    }
    int col = w * 64 + lane;

    for (int s = 0; s < SS; ++s) {
      const unsigned long long* src = hg + (size_t)(s & 1) * 1024 + col;
      unsigned long long rv0, rv1, rv2, rv3;
      for (;;) {
        rv0 = __hip_atomic_load(src,       __ATOMIC_RELAXED, __HIP_MEMORY_SCOPE_AGENT);
        rv1 = __hip_atomic_load(src + 256, __ATOMIC_RELAXED, __HIP_MEMORY_SCOPE_AGENT);
        rv2 = __hip_atomic_load(src + 512, __ATOMIC_RELAXED, __HIP_MEMORY_SCOPE_AGENT);
        rv3 = __hip_atomic_load(src + 768, __ATOMIC_RELAXED, __HIP_MEMORY_SCOPE_AGENT);
        unsigned t = ((unsigned)(rv0 >> 32) ^ (unsigned)s) |
                     ((unsigned)(rv1 >> 32) ^ (unsigned)s) |
                     ((unsigned)(rv2 >> 32) ^ (unsigned)s) |
                     ((unsigned)(rv3 >> 32) ^ (unsigned)s);
        if (__all(t == 0u)) break;
      }
      {
        unsigned l0 = (unsigned)rv0, l1 = (unsigned)rv1,
                 l2 = (unsigned)rv2, l3 = (unsigned)rv3;
        float f0, f1, f2, f3;
        __builtin_memcpy(&f0, &l0, 4); __builtin_memcpy(&f1, &l1, 4);
        __builtin_memcpy(&f2, &l2, 4); __builtin_memcpy(&f3, &l3, 4);
        h_sh[0][col] = f0; h_sh[1][col] = f1;
        h_sh[2][col] = f2; h_sh[3][col] = f3;
      }

      float acc[2][4] = {{0.f,0.f,0.f,0.f},{0.f,0.f,0.f,0.f}};
      #pragma unroll
      for (int j = 0; j < 16; j++) {
        int k4 = w * 64 + j * 4;
        float4 hb0 = *(const float4*)&h_sh[0][k4];
        float4 hb1 = *(const float4*)&h_sh[1][k4];
        float4 hb2 = *(const float4*)&h_sh[2][k4];
        float4 hb3 = *(const float4*)&h_sh[3][k4];
        #pragma unroll
        for (int i = 0; i < 2; i++) {
          float4 wv = wreg[i][j];
          acc[i][0] += wv.x * hb0.x + wv.y * hb0.y + wv.z * hb0.z + wv.w * hb0.w;
          acc[i][1] += wv.x * hb1.x + wv.y * hb1.y + wv.z * hb1.z + wv.w * hb1.w;
          acc[i][2] += wv.x * hb2.x + wv.y * hb2.y + wv.z * hb2.z + wv.w * hb2.w;
          acc[i][3] += wv.x * hb3.x + wv.y * hb3.y + wv.z * hb3.z + wv.w * hb3.w;
        }
      }
      #pragma unroll
      for (int i = 0; i < 2; i++)
        #pragma unroll
        for (int b = 0; b < 4; b++)
          part[s & 1][w][b][i0 + i][c] = acc[i][b];

      block_sync_lds();
    }
  } else {
    int b0l = bp * 2;
    int gb0 = g * 4 + b0l, gb1 = gb0 + 1;
    int colp = cg * 32 + c;
    float c0 = 0.f, c1 = 0.f;
    float xg0[4], xg1[4];
    {
      int tpos = dir ? (SS - 1) : 0;
      const float* xp0 = xsd + (size_t)(tpos * BB + gb0) * G4 + colp;
      const float* xp1 = xsd + (size_t)(tpos * BB + gb1) * G4 + colp;
      #pragma unroll
      for (int i = 0; i < 4; i++) { xg0[i] = xp0[i * 256]; xg1[i] = xp1[i * 256]; }
    }

    for (int s = 0; s < SS; ++s) {
      block_sync_lds();

      float gv0[4], gv1[4];
      #pragma unroll
      for (int i = 0; i < 4; i++) {
        float s0 = xg0[i], s1 = xg1[i];
        #pragma unroll
        for (int ww = 0; ww < 4; ww++) {
          s0 += part[s & 1][ww][b0l][i][c];
          s1 += part[s & 1][ww][b0l + 1][i][c];
        }
        gv0[i] = s0; gv1[i] = s1;
      }
      float hv0, hv1;
      { float ig = fsig(gv0[0]), fg = fsig(gv0[1]);
        float gg = ftanh(gv0[2]), og = fsig(gv0[3]);
        c0 = fg * c0 + ig * gg; hv0 = og * ftanh(c0); }
      { float ig = fsig(gv1[0]), fg = fsig(gv1[1]);
        float gg = ftanh(gv1[2]), og = fsig(gv1[3]);
        c1 = fg * c1 + ig * gg; hv1 = og * ftanh(c1); }

      unsigned hb0, hb1;
      __builtin_memcpy(&hb0, &hv0, 4); __builtin_memcpy(&hb1, &hv1, 4);
      unsigned long long tagw = (unsigned long long)(unsigned)(s + 1) << 32;
      unsigned long long* dst = hg + (size_t)((s + 1) & 1) * 1024 + colp;
      __hip_atomic_store(dst + (size_t)b0l * 256,      tagw | hb0,
                         __ATOMIC_RELAXED, __HIP_MEMORY_SCOPE_AGENT);
      __hip_atomic_store(dst + (size_t)(b0l + 1) * 256, tagw | hb1,
                         __ATOMIC_RELAXED, __HIP_MEMORY_SCOPE_AGENT);

      int tpos = dir ? (SS - 1 - s) : s;
      hout[((size_t)(gb0 * SS + tpos)) * 512 + dir * 256 + colp] = hv0;
      hout[((size_t)(gb1 * SS + tpos)) * 512 + dir * 256 + colp] = hv1;

      if (s + 1 < SS) {
        int tpn = dir ? (SS - 2 - s) : (s + 1);
        const float* xp0 = xsd + (size_t)(tpn * BB + gb0) * G4 + colp;
        const float* xp1 = xsd + (size_t)(tpn * BB + gb1) * G4 + colp;
        #pragma unroll
        for (int i = 0; i < 4; i++) { xg0[i] = xp0[i * 256]; xg1[i] = xp1[i * 256]; }
      }
    }
  }
}

// ---------------- emission features ----------------
__global__ void feats_kernel(const float* __restrict__ h1, const float* __restrict__ wout,
                             const float* __restrict__ bout, float* __restrict__ feats) {
  int bs = blockIdx.x;
  int lane = threadIdx.x;
  const float* hp = h1 + (size_t)bs * 512;
  float hv[8];
  #pragma unroll
  for (int i = 0; i < 8; i++) hv[i] = hp[lane + i * 64];
  #pragma unroll
  for (int t = 0; t < TT; t++) {
    const float* wp = wout + t * 512;
    float p = 0.f;
    #pragma unroll
    for (int i = 0; i < 8; i++) p += hv[i] * wp[lane + i * 64];
    #pragma unroll
    for (int off = 32; off >= 1; off >>= 1) p += __shfl_down(p, off, 64);
    if (lane == 0) feats[(size_t)bs * TT + t] = p + bout[t];
  }
}

// ---------------- Viterbi decode ----------------
__global__ void viterbi_kernel(const float* __restrict__ feats, const float* __restrict__ trans,
                               float* __restrict__ out) {
  int b = blockIdx.x;
  int lane = threadIdx.x;
  __shared__ float tr[121];
  __shared__ float fch[32 * TT];
  __shared__ unsigned char bp[SS][12];
  __shared__ unsigned char path[SS];
  for (int i = lane; i < 121; i += 64) tr[i] = trans[i];
  __syncthreads();
  int ln = lane < TT ? lane : (TT - 1);
  float trr[TT];
  #pragma unroll
  for (int p = 0; p < TT; p++) trr[p] = tr[ln * TT + p];
  float fv = (lane == 9) ? 0.f : NEGV;   // START = 9
  const float* fb = feats + (size_t)b * SS * TT;

  for (int s = 0; s < SS; s++) {
    if ((s & 31) == 0) {
      __syncthreads();
      for (int i = lane; i < 32 * TT; i += 64) fch[i] = fb[s * TT + i];
      __syncthreads();
    }
    float best = -3.0e38f; int arg = 0;
    #pragma unroll
    for (int p = 0; p < TT; p++) {
      float v = __shfl(fv, p, 64) + trr[p];
      if (v > best) { best = v; arg = p; }   // strict > keeps FIRST max (numpy argmax)
    }
    if (lane < TT) bp[s][lane] = (unsigned char)arg;
    fv = best + fch[(s & 31) * TT + ln];
  }
  float term = fv + tr[10 * TT + ln];        // STOP = 10
  float best = -3.0e38f; int arg = 0;
  #pragma unroll
  for (int p = 0; p < TT; p++) {
    float v = __shfl(term, p, 64);
    if (v > best) { best = v; arg = p; }
  }
  __syncthreads();
  if (lane == 0) {
    out[b] = best;
    int tg = arg;
    path[SS - 1] = (unsigned char)tg;
    for (int s = SS - 1; s >= 1; s--) {
      tg = bp[s][tg];
      path[s - 1] = (unsigned char)tg;
    }
  }
  __syncthreads();
  for (int i = lane; i < SS; i += 64) out[32 + b * SS + i] = (float)path[i];
}

// ---------------- launcher ----------------
extern "C" void kernel_launch(void* const* d_in, const int* in_sizes, int n_in,
                              void* d_out, int out_size, void* d_ws, size_t ws_size,
                              hipStream_t stream) {
  const int*   x     = (const int*)d_in[0];
  const float* emb   = (const float*)d_in[2];
  const float* wih0f = (const float*)d_in[3];
  const float* whh0f = (const float*)d_in[4];
  const float* b0f   = (const float*)d_in[5];
  const float* wih0b = (const float*)d_in[6];
  const float* whh0b = (const float*)d_in[7];
  const float* b0b   = (const float*)d_in[8];
  const float* wih1f = (const float*)d_in[9];
  const float* whh1f = (const float*)d_in[10];
  const float* b1f   = (const float*)d_in[11];
  const float* wih1b = (const float*)d_in[12];
  const float* whh1b = (const float*)d_in[13];
  const float* b1b   = (const float*)d_in[14];
  const float* wout  = (const float*)d_in[15];
  const float* bout  = (const float*)d_in[16];
  const float* trans = (const float*)d_in[17];

  char* ws = (char*)d_ws;
  unsigned short* xeh = (unsigned short*)(ws + OFF_XEH);
  unsigned short* xel = (unsigned short*)(ws + OFF_XEL);
  float* xs    = (float*)(ws + OFF_XS);
  float* h0    = (float*)(ws + OFF_H0);
  float* h1    = (float*)(ws + OFF_H1);
  unsigned short* h0h = (unsigned short*)(ws + OFF_H1);               // overlay (dead until scan1)
  unsigned short* h0l = (unsigned short*)(ws + OFF_H1 + 16777216ull);
  float* feats = (float*)(ws + OFF_FEATS);
  unsigned long long* hgrp = (unsigned long long*)(ws + OFF_HGRP);
  unsigned short* w0h = (unsigned short*)(ws + OFF_W0H);
  unsigned short* w0l = (unsigned short*)(ws + OFF_W0L);
  unsigned short* w1h = (unsigned short*)(ws + OFF_W1H);
  unsigned short* w1l = (unsigned short*)(ws + OFF_W1L);
  float* outp  = (float*)d_out;

  // embedding gather + hi/lo split
  emb_kernel<<<4096, 256, 0, stream>>>(x, (const float4*)emb, (ushort4*)xeh, (ushort4*)xel);
  // weight splits: wih0 [2][1024][256], wih1 [2][1024][512]
  split_kernel<<<256, 256, 0, stream>>>((const float4*)wih0f, (ushort4*)w0h, (ushort4*)w0l, 65536);
  split_kernel<<<256, 256, 0, stream>>>((const float4*)wih0b, (ushort4*)(w0h + 262144),
                                        (ushort4*)(w0l + 262144), 65536);
  split_kernel<<<512, 256, 0, stream>>>((const float4*)wih1f, (ushort4*)w1h, (ushort4*)w1l, 131072);
  split_kernel<<<512, 256, 0, stream>>>((const float4*)wih1b, (ushort4*)(w1h + 524288),
                                        (ushort4*)(w1l + 524288), 131072);

  proj_mfma<256><<<dim3(256, 8, 2), 256, 0, stream>>>(xeh, xel, w0h, w0l, b0f, b0b, xs);
  hipMemsetAsync(hgrp, 0, 1048576, stream);   // tag 0 == initial h(0) = 0
  scan_kernel<<<dim3(8, 8, 2), 320, 0, stream>>>(xs, whh0f, whh0b, hgrp, h0);

  split_kernel<<<8192, 256, 0, stream>>>((const float4*)h0, (ushort4*)h0h, (ushort4*)h0l, 2097152);
  proj_mfma<512><<<dim3(256, 8, 2), 256, 0, stream>>>(h0h, h0l, w1h, w1l, b1f, b1b, xs);
  hipMemsetAsync(hgrp, 0, 1048576, stream);
  scan_kernel<<<dim3(8, 8, 2), 320, 0, stream>>>(xs, whh1f, whh1b, hgrp, h1);

  feats_kernel<<<BB * SS, 64, 0, stream>>>(h1, wout, bout, feats);
  viterbi_kernel<<<BB, 64, 0, stream>>>(feats, trans, outp);
}